// Round 5
// baseline (232.069 us; speedup 1.0000x reference)
//
#include <hip/hip_runtime.h>
#include <hip/hip_bf16.h>

#define DI __device__ __forceinline__

typedef __bf16 bf16x8 __attribute__((ext_vector_type(8)));
typedef float  f32x4  __attribute__((ext_vector_type(4)));
typedef float  f32x16 __attribute__((ext_vector_type(16)));

// B=4, T=32, S=256, E=512, H=8, D=64; M = B*T*S = 32768; SCALE = 8.

DI ushort f2bf(float f) {
  union { float f; unsigned u; } v; v.f = f;
  unsigned r = v.u + 0x7fffu + ((v.u >> 16) & 1u);
  return (ushort)(r >> 16);
}

DI unsigned cvtpk2(float a, float b) {  // [bf16(a) | bf16(b)<<16], RNE
  unsigned r;
  asm("v_cvt_pk_bf16_f32 %0, %1, %2" : "=v"(r) : "v"(a), "v"(b));
  return r;
}

DI float rcpf(float x) {
  float r;
  asm("v_rcp_f32 %0, %1" : "=v"(r) : "v"(x));
  return r;
}

DI void gload_lds16(const void* g, void* lds) {
  __builtin_amdgcn_global_load_lds(
      (const __attribute__((address_space(1))) unsigned*)g,
      (__attribute__((address_space(3))) unsigned*)lds, 16, 0, 0);
}

DI f32x4 zero4() { f32x4 z; z[0] = 0.f; z[1] = 0.f; z[2] = 0.f; z[3] = 0.f; return z; }

DI f32x16 zero16() {
  f32x16 z;
  for (int i = 0; i < 16; i++) z[i] = 0.f;
  return z;
}

union BF8U { ushort u[8]; unsigned d[4]; bf16x8 v; };

// ---------------- weight transpose: W[k][n] f32 -> Wt[n][k] bf16 (4 matrices) --------
__global__ __launch_bounds__(256) void wtrans_kernel(
    const float* __restrict__ W0, const float* __restrict__ W1,
    const float* __restrict__ W2, const float* __restrict__ W3,
    ushort* __restrict__ out) {
  __shared__ float tile[64][65];
  const float* W = blockIdx.z == 0 ? W0 : blockIdx.z == 1 ? W1 : blockIdx.z == 2 ? W2 : W3;
  ushort* o = out + (size_t)blockIdx.z * 512 * 512;
  int k0 = blockIdx.x * 64, n0 = blockIdx.y * 64;
  int tid = threadIdx.x;
#pragma unroll
  for (int i = 0; i < 16; i++) {
    int idx = i * 256 + tid; int r = idx >> 6, c = idx & 63;
    tile[r][c] = W[(size_t)(k0 + r) * 512 + n0 + c];
  }
  __syncthreads();
#pragma unroll
  for (int i = 0; i < 16; i++) {
    int idx = i * 256 + tid; int r = idx >> 6, c = idx & 63;
    o[(size_t)(n0 + r) * 512 + k0 + c] = f2bf(tile[c][r]);
  }
}

// ---------------- pipelined GEMM core: 128x128 tile, BK=64, double-buffered LDS -------
// One barrier per K-step; tile t+1 prefetched at top of step t. B (and A when bf16)
// staged via global_load_lds with pre-swizzled source (content lands XOR-swizzled);
// fp32 A staged via regs -> cvt_pk -> swizzled ds_write placed AFTER the MFMAs.
template <int AF32>
DI void gemm_core(const void* Ap, const ushort* __restrict__ Bt, int m0, int n0,
                  char* AldsBase, char* BldsBase, f32x4 (&acc)[4][4]) {
  const float*  Af = (const float*)Ap;
  const ushort* Ah = (const ushort*)Ap;
  int tid = threadIdx.x, lane = tid & 63, wv = tid >> 6;
  int wm = (wv >> 1) * 64, wn = (wv & 1) * 64;
  int srow = tid >> 3, skg = tid & 7;

  float4 ar[8];

  auto issueB = [&](int t, char* Bb) {
#pragma unroll
    for (int i = 0; i < 4; i++) {
      int c = (wv * 4 + i) * 64 + lane;
      int r = c >> 3, g = (c & 7) ^ (r & 7);
      gload_lds16(Bt + (size_t)(n0 + r) * 512 + t * 64 + g * 8, Bb + (wv * 4 + i) * 1024);
    }
  };
  auto issueA_bf16 = [&](int t, char* Ab) {
#pragma unroll
    for (int i = 0; i < 4; i++) {
      int c = (wv * 4 + i) * 64 + lane;
      int r = c >> 3, g = (c & 7) ^ (r & 7);
      gload_lds16(Ah + (size_t)(m0 + r) * 512 + t * 64 + g * 8, Ab + (wv * 4 + i) * 1024);
    }
  };
  auto issueA_f32 = [&](int t) {
#pragma unroll
    for (int rr = 0; rr < 4; rr++) {
      const float4* p = (const float4*)(Af + (size_t)(m0 + srow + rr * 32) * 512 + t * 64 + skg * 8);
      ar[rr * 2] = p[0]; ar[rr * 2 + 1] = p[1];
    }
  };
  auto writeA_f32 = [&](char* Ab) {
#pragma unroll
    for (int rr = 0; rr < 4; rr++) {
      int r = srow + rr * 32;
      BF8U av;
      av.d[0] = cvtpk2(ar[rr * 2].x, ar[rr * 2].y);
      av.d[1] = cvtpk2(ar[rr * 2].z, ar[rr * 2].w);
      av.d[2] = cvtpk2(ar[rr * 2 + 1].x, ar[rr * 2 + 1].y);
      av.d[3] = cvtpk2(ar[rr * 2 + 1].z, ar[rr * 2 + 1].w);
      *(bf16x8*)(Ab + ((r * 128 + skg * 16) ^ ((r & 7) << 4))) = av.v;
    }
  };
  auto compute = [&](char* Ab, char* Bb) {
#pragma unroll
    for (int ks = 0; ks < 2; ks++) {
      bf16x8 a[4], b[4];
#pragma unroll
      for (int i = 0; i < 4; i++) {
        int ra = wm + i * 16 + (lane & 15);
        a[i] = *(const bf16x8*)(Ab + ((ra * 128 + (ks * 4 + (lane >> 4)) * 16) ^ ((ra & 7) << 4)));
        int rb = wn + i * 16 + (lane & 15);
        b[i] = *(const bf16x8*)(Bb + ((rb * 128 + (ks * 4 + (lane >> 4)) * 16) ^ ((rb & 7) << 4)));
      }
#pragma unroll
      for (int i = 0; i < 4; i++)
#pragma unroll
        for (int j = 0; j < 4; j++)
          acc[i][j] = __builtin_amdgcn_mfma_f32_16x16x32_bf16(a[i], b[j], acc[i][j], 0, 0, 0);
    }
  };

  // prologue: stage tile 0
  if (AF32) { issueA_f32(0); writeA_f32(AldsBase); }
  else issueA_bf16(0, AldsBase);
  issueB(0, BldsBase);
  __syncthreads();

#pragma unroll
  for (int t = 0; t < 8; t++) {
    char* Ab = AldsBase + (t & 1) * 16384;
    char* Bb = BldsBase + (t & 1) * 16384;
    char* An = AldsBase + (((t & 1) ^ 1)) * 16384;
    char* Bn = BldsBase + (((t & 1) ^ 1)) * 16384;
    if (t < 7) {
      if (AF32) issueA_f32(t + 1);
      else issueA_bf16(t + 1, An);
      issueB(t + 1, Bn);
    }
    compute(Ab, Bb);
    if (t < 7 && AF32) writeA_f32(An);
    __syncthreads();
  }
}

// ---------------- fused Q/K/V projection GEMMs (blockIdx.z selects modality) --------
__global__ __launch_bounds__(256) void qkv_gemm_kernel(
    const float* __restrict__ Aq, const float* __restrict__ Ak, const float* __restrict__ Av,
    const ushort* __restrict__ Wt, const float* __restrict__ bqp,
    const float* __restrict__ bkp, const float* __restrict__ bvp,
    ushort* __restrict__ Qw, ushort* __restrict__ Kw, ushort* __restrict__ Vt) {
  __shared__ __align__(16) char Alds[32768];
  __shared__ __align__(16) char Blds[32768];
  int z = blockIdx.z;
  const float* A = z == 0 ? Aq : z == 1 ? Ak : Av;
  const ushort* Bt = Wt + (size_t)z * 262144;
  const float* bias = z == 0 ? bqp : z == 1 ? bkp : bvp;
  int bl = ((int)blockIdx.x & 7) * 128 + ((int)blockIdx.x >> 3);
  int m0 = (bl >> 2) * 128, n0 = (bl & 3) * 128;

  f32x4 acc[4][4];
#pragma unroll
  for (int i = 0; i < 4; i++)
#pragma unroll
    for (int j = 0; j < 4; j++) acc[i][j] = zero4();

  gemm_core<1>(A, Bt, m0, n0, Alds, Blds, acc);

  int lane = threadIdx.x & 63, wv = threadIdx.x >> 6;
  int wm = (wv >> 1) * 64, wn = (wv & 1) * 64;
#pragma unroll
  for (int j = 0; j < 4; j++) {
    int col = n0 + wn + j * 16 + (lane & 15);
    float bv = bias[col];
#pragma unroll
    for (int i = 0; i < 4; i++) {
      int row0 = m0 + wm + i * 16 + (lane >> 4) * 4;
      if (z == 2) {
        int btv = row0 >> 8, s = row0 & 255;
        ushort4 w;
        w.x = f2bf(acc[i][j][0] + bv); w.y = f2bf(acc[i][j][1] + bv);
        w.z = f2bf(acc[i][j][2] + bv); w.w = f2bf(acc[i][j][3] + bv);
        *(ushort4*)(Vt + ((size_t)btv * 512 + col) * 256 + s) = w;
      } else {
        ushort* C = z == 0 ? Qw : Kw;
#pragma unroll
        for (int r = 0; r < 4; r++)
          C[(size_t)(row0 + r) * 512 + col] = f2bf(acc[i][j][r] + bv);
      }
    }
  }
}

// ---------------- output GEMM: bf16 A, f32 out ---------------------------------------
__global__ __launch_bounds__(256) void out_gemm_kernel(
    const ushort* __restrict__ A, const ushort* __restrict__ Bt,
    const float* __restrict__ bias, float* __restrict__ C) {
  __shared__ __align__(16) char Alds[32768];
  __shared__ __align__(16) char Blds[32768];
  int bl = ((int)blockIdx.x & 7) * 128 + ((int)blockIdx.x >> 3);
  int m0 = (bl >> 2) * 128, n0 = (bl & 3) * 128;

  f32x4 acc[4][4];
#pragma unroll
  for (int i = 0; i < 4; i++)
#pragma unroll
    for (int j = 0; j < 4; j++) acc[i][j] = zero4();

  gemm_core<0>(A, Bt, m0, n0, Alds, Blds, acc);

  int lane = threadIdx.x & 63, wv = threadIdx.x >> 6;
  int wm = (wv >> 1) * 64, wn = (wv & 1) * 64;
#pragma unroll
  for (int j = 0; j < 4; j++) {
    int col = n0 + wn + j * 16 + (lane & 15);
    float bv = bias[col];
#pragma unroll
    for (int i = 0; i < 4; i++) {
      int row0 = m0 + wm + i * 16 + (lane >> 4) * 4;
#pragma unroll
      for (int r = 0; r < 4; r++)
        C[(size_t)(row0 + r) * 512 + col] = acc[i][j][r] + bv;
    }
  }
}

// ---------------- attention: block = (bt,h), 4 waves x 64 q rows -------------------
// K and V staged ONCE into LDS via global_load_lds in fragment-read order; V staging
// issued after the K-barrier, drains at the pass-A/pass-B barrier (hidden under pass A).
// Swapped S^T = mfma(K,Q): lane owns q = lane&31; P packed bf16 in-register,
// PV A-frags assembled via shfl_xor(32) + select. temporal_sync cancels.
__global__ __launch_bounds__(256) void attn_kernel(
    const ushort* __restrict__ Q, const ushort* __restrict__ K,
    const ushort* __restrict__ Vt, const float* __restrict__ mw,
    ushort* __restrict__ att) {
  __shared__ __align__(16) char Klds[32768];  // [kt][ds][hi][lq] 16B chunks
  __shared__ __align__(16) char Vlds[32768];  // [kt][ks][df][hi][lq] 16B chunks
  int tid = threadIdx.x, lane = tid & 63, wv = tid >> 6;
  int lq = lane & 31, hi = lane >> 5;
  int b = blockIdx.x;          // 1024 = 128 bt x 8 h
  int h = b & 7, bt = b >> 3;
  const ushort* Qb = Q + ((size_t)bt * 256 + wv * 64) * 512 + h * 64;
  const ushort* Kb = K + ((size_t)bt * 256) * 512 + h * 64;
  const ushort* Vb = Vt + ((size_t)bt * 512 + h * 64) * 256;
  float c0 = mw[h] * mw[8 + h] * 0.125f;

  // stage K: 32 x 1KB instrs across 4 waves, LDS order == fragment-read order
#pragma unroll
  for (int i = 0; i < 8; i++) {
    int ci = (wv * 8 + i) * 64 + lane;
    int l2 = ci & 31, h2 = (ci >> 5) & 1, ds = (ci >> 6) & 3, kt = ci >> 8;
    gload_lds16(Kb + (size_t)(kt * 32 + l2) * 512 + ds * 16 + h2 * 8,
                &Klds[(wv * 8 + i) * 1024]);
  }
  // hoist Q as B-operand fragments (global, drains at first barrier)
  bf16x8 qf[2][4];
#pragma unroll
  for (int qj = 0; qj < 2; qj++)
#pragma unroll
    for (int ds = 0; ds < 4; ds++)
      qf[qj][ds] = *(const bf16x8*)(Qb + (size_t)(qj * 32 + lq) * 512 + ds * 16 + hi * 8);
  __syncthreads();

  // issue V staging now; it drains at the next barrier (hidden under pass A)
#pragma unroll
  for (int i = 0; i < 8; i++) {
    int ci = (wv * 8 + i) * 64 + lane;
    int l2 = ci & 31, h2 = (ci >> 5) & 1, df = (ci >> 6) & 1, ks = (ci >> 7) & 1, kt = ci >> 8;
    gload_lds16(Vb + (size_t)(df * 32 + l2) * 256 + kt * 32 + ks * 16 + h2 * 8,
                &Vlds[(wv * 8 + i) * 1024]);
  }

  // ---- pass A: row max of c0 * (Q.K), K from LDS ----
  float mx[2] = {-3.0e38f, -3.0e38f};
#pragma unroll 2
  for (int kt = 0; kt < 8; kt++) {
    bf16x8 kf[4];
#pragma unroll
    for (int ds = 0; ds < 4; ds++)
      kf[ds] = *(const bf16x8*)(&Klds[((kt * 4 + ds) * 2 + hi) * 512 + lq * 16]);
#pragma unroll
    for (int qj = 0; qj < 2; qj++) {
      f32x16 sT = zero16();
#pragma unroll
      for (int ds = 0; ds < 4; ds++)
        sT = __builtin_amdgcn_mfma_f32_32x32x16_bf16(kf[ds], qf[qj][ds], sT, 0, 0, 0);
#pragma unroll
      for (int r = 0; r < 16; r++) mx[qj] = fmaxf(mx[qj], sT[r] * c0);
    }
  }
#pragma unroll
  for (int qj = 0; qj < 2; qj++) mx[qj] = fmaxf(mx[qj], __shfl_xor(mx[qj], 32, 64));
  __syncthreads();   // V staged

  // ---- pass B: p = sigmoid(5*(s*c0 - mx)); row-sum and P.V ----
  float a5 = 5.f * c0;
  float m5[2] = {5.f * mx[0], 5.f * mx[1]};
  float sm[2] = {0.f, 0.f};
  f32x16 acc[2][2];
  acc[0][0] = zero16(); acc[0][1] = zero16(); acc[1][0] = zero16(); acc[1][1] = zero16();

#pragma unroll 2
  for (int kt = 0; kt < 8; kt++) {
    bf16x8 kf[4], vf[2][2];
#pragma unroll
    for (int ds = 0; ds < 4; ds++)
      kf[ds] = *(const bf16x8*)(&Klds[((kt * 4 + ds) * 2 + hi) * 512 + lq * 16]);
#pragma unroll
    for (int ks = 0; ks < 2; ks++)
#pragma unroll
      for (int df = 0; df < 2; df++)
        vf[ks][df] = *(const bf16x8*)(&Vlds[(((kt * 2 + ks) * 2 + df) * 2 + hi) * 512 + lq * 16]);
#pragma unroll
    for (int qj = 0; qj < 2; qj++) {
      f32x16 sT = zero16();
#pragma unroll
      for (int ds = 0; ds < 4; ds++)
        sT = __builtin_amdgcn_mfma_f32_32x32x16_bf16(kf[ds], qf[qj][ds], sT, 0, 0, 0);
      unsigned pk[8];
#pragma unroll
      for (int i = 0; i < 8; i++) {
        float p0 = rcpf(1.f + __expf(m5[qj] - sT[2 * i] * a5));
        float p1 = rcpf(1.f + __expf(m5[qj] - sT[2 * i + 1] * a5));
        sm[qj] += p0 + p1;
        pk[i] = cvtpk2(p0, p1);
      }
      // reg r holds k = (r&3) + 8*(r>>2) + 4*hi (+32*kt). Assemble A-frags:
#pragma unroll
      for (int ks = 0; ks < 2; ks++) {
        int bb = ks * 4;
        unsigned sa = (unsigned)__shfl_xor((int)pk[bb + 0], 32, 64);
        unsigned sb = (unsigned)__shfl_xor((int)pk[bb + 1], 32, 64);
        unsigned sc = (unsigned)__shfl_xor((int)pk[bb + 2], 32, 64);
        unsigned sd = (unsigned)__shfl_xor((int)pk[bb + 3], 32, 64);
        BF8U pa;
        pa.d[0] = hi ? sc : pk[bb + 0];
        pa.d[1] = hi ? sd : pk[bb + 1];
        pa.d[2] = hi ? pk[bb + 2] : sa;
        pa.d[3] = hi ? pk[bb + 3] : sb;
#pragma unroll
        for (int df = 0; df < 2; df++)
          acc[qj][df] = __builtin_amdgcn_mfma_f32_32x32x16_bf16(pa.v, vf[ks][df], acc[qj][df], 0, 0, 0);
      }
    }
  }

  // ---- epilogue: normalize by row-sum, write att[m][f] bf16 ----
#pragma unroll
  for (int qj = 0; qj < 2; qj++) sm[qj] += __shfl_xor(sm[qj], 32, 64);
  float rs[2] = {rcpf(sm[0] + 1e-8f), rcpf(sm[1] + 1e-8f)};
#pragma unroll
  for (int qj = 0; qj < 2; qj++) {
#pragma unroll
    for (int r = 0; r < 16; r++) {
      int ql = (r & 3) + 8 * (r >> 2) + 4 * hi;
      float rr = __shfl(rs[qj], ql, 64);
      size_t rowbase = ((size_t)bt * 256 + wv * 64 + qj * 32 + ql) * 512 + h * 64;
#pragma unroll
      for (int df = 0; df < 2; df++)
        att[rowbase + df * 32 + lq] = f2bf(acc[qj][df][r] * rr);
    }
  }
}

extern "C" void kernel_launch(void* const* d_in, const int* in_sizes, int n_in,
                              void* d_out, int out_size, void* d_ws, size_t ws_size,
                              hipStream_t stream) {
  (void)in_sizes; (void)n_in; (void)out_size; (void)ws_size;
  const float* qs  = (const float*)d_in[0];
  const float* ksn = (const float*)d_in[1];
  const float* vsn = (const float*)d_in[2];
  const float* Wq  = (const float*)d_in[3];
  const float* bq  = (const float*)d_in[4];
  const float* Wk  = (const float*)d_in[5];
  const float* bk  = (const float*)d_in[6];
  const float* Wv  = (const float*)d_in[7];
  const float* bv  = (const float*)d_in[8];
  const float* Wo  = (const float*)d_in[9];
  const float* bo  = (const float*)d_in[10];
  const float* mw  = (const float*)d_in[11];
  // d_in[12] = temporal_sync: constant along key axis -> cancels in spike softmax.

  char* ws = (char*)d_ws;
  ushort* Wt = (ushort*)ws;                                   // 4 * 512KiB bf16
  ushort* Qw = (ushort*)(ws + (size_t)(2u << 20));
  ushort* Kw = (ushort*)(ws + (size_t)(2u << 20) + 33554432u);
  ushort* Vt = (ushort*)(ws + (size_t)(2u << 20) + 2u * 33554432u);
  ushort* Aw = (ushort*)(ws + (size_t)(2u << 20) + 3u * 33554432u);

  wtrans_kernel<<<dim3(8, 8, 4), 256, 0, stream>>>(Wq, Wk, Wv, Wo, Wt);
  qkv_gemm_kernel<<<dim3(1024, 1, 3), 256, 0, stream>>>(qs, ksn, vsn, Wt, bq, bk, bv,
                                                        Qw, Kw, Vt);
  attn_kernel<<<dim3(1024), 256, 0, stream>>>(Qw, Kw, Vt, mw, Aw);
  out_gemm_kernel<<<dim3(1024), 256, 0, stream>>>(Aw, Wt + 3 * 262144, bo, (float*)d_out);
}

// Round 6
// 212.247 us; speedup vs baseline: 1.0934x; 1.0934x over previous
//
#include <hip/hip_runtime.h>
#include <hip/hip_bf16.h>

#define DI __device__ __forceinline__

typedef __bf16 bf16x8 __attribute__((ext_vector_type(8)));
typedef float  f32x4  __attribute__((ext_vector_type(4)));
typedef float  f32x16 __attribute__((ext_vector_type(16)));

// B=4, T=32, S=256, E=512, H=8, D=64; M = B*T*S = 32768; SCALE = 8.

DI ushort f2bf(float f) {
  union { float f; unsigned u; } v; v.f = f;
  unsigned r = v.u + 0x7fffu + ((v.u >> 16) & 1u);
  return (ushort)(r >> 16);
}

DI unsigned cvtpk2(float a, float b) {  // [bf16(a) | bf16(b)<<16], RNE
  unsigned r;
  asm("v_cvt_pk_bf16_f32 %0, %1, %2" : "=v"(r) : "v"(a), "v"(b));
  return r;
}

DI float rcpf(float x) {
  float r;
  asm("v_rcp_f32 %0, %1" : "=v"(r) : "v"(x));
  return r;
}

DI void gload_lds16(const void* g, void* lds) {
  __builtin_amdgcn_global_load_lds(
      (const __attribute__((address_space(1))) unsigned*)g,
      (__attribute__((address_space(3))) unsigned*)lds, 16, 0, 0);
}

DI f32x4 zero4() { f32x4 z; z[0] = 0.f; z[1] = 0.f; z[2] = 0.f; z[3] = 0.f; return z; }

DI f32x16 zero16() {
  f32x16 z;
  for (int i = 0; i < 16; i++) z[i] = 0.f;
  return z;
}

union BF8U { ushort u[8]; unsigned d[4]; bf16x8 v; };

// ---------------- weight transpose: W[k][n] f32 -> Wt[n][k] bf16 (4 matrices) --------
__global__ __launch_bounds__(256) void wtrans_kernel(
    const float* __restrict__ W0, const float* __restrict__ W1,
    const float* __restrict__ W2, const float* __restrict__ W3,
    ushort* __restrict__ out) {
  __shared__ float tile[64][65];
  const float* W = blockIdx.z == 0 ? W0 : blockIdx.z == 1 ? W1 : blockIdx.z == 2 ? W2 : W3;
  ushort* o = out + (size_t)blockIdx.z * 512 * 512;
  int k0 = blockIdx.x * 64, n0 = blockIdx.y * 64;
  int tid = threadIdx.x;
#pragma unroll
  for (int i = 0; i < 16; i++) {
    int idx = i * 256 + tid; int r = idx >> 6, c = idx & 63;
    tile[r][c] = W[(size_t)(k0 + r) * 512 + n0 + c];
  }
  __syncthreads();
#pragma unroll
  for (int i = 0; i < 16; i++) {
    int idx = i * 256 + tid; int r = idx >> 6, c = idx & 63;
    o[(size_t)(n0 + r) * 512 + k0 + c] = f2bf(tile[c][r]);
  }
}

// ---------------- GEMM core: 128x128 tile, BK=64 ------------------------------------
// A: single-buffered 16KB LDS, register-staged prefetch (loads for t+1 issued before
// compute(t); cvt + ds_write after the first barrier, where the mandatory vmcnt drain
// lands anyway). B: global_load_lds direct into a 32KB double buffer, source
// pre-swizzled so reads stay conflict-free. 48KB total -> 3 blocks/CU.
template <int AF32>
DI void gemm_core(const void* Ap, const ushort* __restrict__ Bt, int m0, int n0,
                  char* Alds, char* Blds, f32x4 (&acc)[4][4]) {
  const float*  Af = (const float*)Ap;
  const ushort* Ah = (const ushort*)Ap;
  int tid = threadIdx.x, lane = tid & 63, wv = tid >> 6;
  int wm = (wv >> 1) * 64, wn = (wv & 1) * 64;
  int srow = tid >> 3, skg = tid & 7;

  float4 ar[8];
  bf16x8 ab[4];

  auto issueB = [&](int t) {
    char* Bb = Blds + (t & 1) * 16384;
#pragma unroll
    for (int i = 0; i < 4; i++) {
      int c = (wv * 4 + i) * 64 + lane;
      int r = c >> 3, g = (c & 7) ^ (r & 7);
      gload_lds16(Bt + (size_t)(n0 + r) * 512 + t * 64 + g * 8, Bb + (wv * 4 + i) * 1024);
    }
  };
  auto loadA = [&](int t) {
    if (AF32) {
#pragma unroll
      for (int rr = 0; rr < 4; rr++) {
        const float4* p = (const float4*)(Af + (size_t)(m0 + srow + rr * 32) * 512 + t * 64 + skg * 8);
        ar[rr * 2] = p[0]; ar[rr * 2 + 1] = p[1];
      }
    } else {
#pragma unroll
      for (int rr = 0; rr < 4; rr++)
        ab[rr] = *(const bf16x8*)(Ah + (size_t)(m0 + srow + rr * 32) * 512 + t * 64 + skg * 8);
    }
  };
  auto writeA = [&]() {
#pragma unroll
    for (int rr = 0; rr < 4; rr++) {
      int r = srow + rr * 32;
      BF8U av;
      if (AF32) {
        av.d[0] = cvtpk2(ar[rr * 2].x, ar[rr * 2].y);
        av.d[1] = cvtpk2(ar[rr * 2].z, ar[rr * 2].w);
        av.d[2] = cvtpk2(ar[rr * 2 + 1].x, ar[rr * 2 + 1].y);
        av.d[3] = cvtpk2(ar[rr * 2 + 1].z, ar[rr * 2 + 1].w);
      } else {
        av.v = ab[rr];
      }
      *(bf16x8*)(Alds + ((r * 128 + skg * 16) ^ ((r & 7) << 4))) = av.v;
    }
  };
  auto compute = [&](int t) {
    char* Bb = Blds + (t & 1) * 16384;
#pragma unroll
    for (int ks = 0; ks < 2; ks++) {
      bf16x8 a[4], b[4];
#pragma unroll
      for (int i = 0; i < 4; i++) {
        int ra = wm + i * 16 + (lane & 15);
        a[i] = *(const bf16x8*)(Alds + ((ra * 128 + (ks * 4 + (lane >> 4)) * 16) ^ ((ra & 7) << 4)));
        int rb = wn + i * 16 + (lane & 15);
        b[i] = *(const bf16x8*)(Bb + ((rb * 128 + (ks * 4 + (lane >> 4)) * 16) ^ ((rb & 7) << 4)));
      }
#pragma unroll
      for (int i = 0; i < 4; i++)
#pragma unroll
        for (int j = 0; j < 4; j++)
          acc[i][j] = __builtin_amdgcn_mfma_f32_16x16x32_bf16(a[i], b[j], acc[i][j], 0, 0, 0);
    }
  };

  // prologue: stage tile 0
  issueB(0); loadA(0); writeA();
  __syncthreads();

#pragma unroll
  for (int t = 0; t < 8; t++) {
    if (t < 7) { issueB(t + 1); loadA(t + 1); }
    compute(t);
    __syncthreads();     // drains vmcnt (t+1 regs + B lds landed); all reads of Alds done
    if (t < 7) writeA();
    __syncthreads();
  }
}

// ---------------- fused Q/K/V projection GEMMs (blockIdx.z selects modality) --------
__global__ __launch_bounds__(256, 3) void qkv_gemm_kernel(
    const float* __restrict__ Aq, const float* __restrict__ Ak, const float* __restrict__ Av,
    const ushort* __restrict__ Wt, const float* __restrict__ bqp,
    const float* __restrict__ bkp, const float* __restrict__ bvp,
    ushort* __restrict__ Qw, ushort* __restrict__ Kw, ushort* __restrict__ Vt) {
  __shared__ __align__(16) char Alds[16384];
  __shared__ __align__(16) char Blds[32768];
  int z = blockIdx.z;
  const float* A = z == 0 ? Aq : z == 1 ? Ak : Av;
  const ushort* Bt = Wt + (size_t)z * 262144;
  const float* bias = z == 0 ? bqp : z == 1 ? bkp : bvp;
  int bl = ((int)blockIdx.x & 7) * 128 + ((int)blockIdx.x >> 3);
  int m0 = (bl >> 2) * 128, n0 = (bl & 3) * 128;

  f32x4 acc[4][4];
#pragma unroll
  for (int i = 0; i < 4; i++)
#pragma unroll
    for (int j = 0; j < 4; j++) acc[i][j] = zero4();

  gemm_core<1>(A, Bt, m0, n0, Alds, Blds, acc);

  int lane = threadIdx.x & 63, wv = threadIdx.x >> 6;
  int wm = (wv >> 1) * 64, wn = (wv & 1) * 64;
#pragma unroll
  for (int j = 0; j < 4; j++) {
    int col = n0 + wn + j * 16 + (lane & 15);
    float bv = bias[col];
#pragma unroll
    for (int i = 0; i < 4; i++) {
      int row0 = m0 + wm + i * 16 + (lane >> 4) * 4;
      if (z == 2) {
        int btv = row0 >> 8, s = row0 & 255;
        ushort4 w;
        w.x = f2bf(acc[i][j][0] + bv); w.y = f2bf(acc[i][j][1] + bv);
        w.z = f2bf(acc[i][j][2] + bv); w.w = f2bf(acc[i][j][3] + bv);
        *(ushort4*)(Vt + ((size_t)btv * 512 + col) * 256 + s) = w;
      } else {
        ushort* C = z == 0 ? Qw : Kw;
#pragma unroll
        for (int r = 0; r < 4; r++)
          C[(size_t)(row0 + r) * 512 + col] = f2bf(acc[i][j][r] + bv);
      }
    }
  }
}

// ---------------- output GEMM: bf16 A, f32 out ---------------------------------------
__global__ __launch_bounds__(256, 3) void out_gemm_kernel(
    const ushort* __restrict__ A, const ushort* __restrict__ Bt,
    const float* __restrict__ bias, float* __restrict__ C) {
  __shared__ __align__(16) char Alds[16384];
  __shared__ __align__(16) char Blds[32768];
  int bl = ((int)blockIdx.x & 7) * 128 + ((int)blockIdx.x >> 3);
  int m0 = (bl >> 2) * 128, n0 = (bl & 3) * 128;

  f32x4 acc[4][4];
#pragma unroll
  for (int i = 0; i < 4; i++)
#pragma unroll
    for (int j = 0; j < 4; j++) acc[i][j] = zero4();

  gemm_core<0>(A, Bt, m0, n0, Alds, Blds, acc);

  int lane = threadIdx.x & 63, wv = threadIdx.x >> 6;
  int wm = (wv >> 1) * 64, wn = (wv & 1) * 64;
#pragma unroll
  for (int j = 0; j < 4; j++) {
    int col = n0 + wn + j * 16 + (lane & 15);
    float bv = bias[col];
#pragma unroll
    for (int i = 0; i < 4; i++) {
      int row0 = m0 + wm + i * 16 + (lane >> 4) * 4;
#pragma unroll
      for (int r = 0; r < 4; r++)
        C[(size_t)(row0 + r) * 512 + col] = acc[i][j][r] + bv;
    }
  }
}

// ---------------- attention: block = (bt,h), 4 waves x 64 q rows -------------------
// K and V staged ONCE into LDS via global_load_lds in fragment-read order; V staging
// issued after the K-barrier, drains at the pass-A/pass-B barrier (hidden under pass A).
// Swapped S^T = mfma(K,Q): lane owns q = lane&31; P packed bf16 in-register,
// PV A-frags assembled via shfl_xor(32) + select. temporal_sync cancels.
__global__ __launch_bounds__(256) void attn_kernel(
    const ushort* __restrict__ Q, const ushort* __restrict__ K,
    const ushort* __restrict__ Vt, const float* __restrict__ mw,
    ushort* __restrict__ att) {
  __shared__ __align__(16) char Klds[32768];  // [kt][ds][hi][lq] 16B chunks
  __shared__ __align__(16) char Vlds[32768];  // [kt][ks][df][hi][lq] 16B chunks
  int tid = threadIdx.x, lane = tid & 63, wv = tid >> 6;
  int lq = lane & 31, hi = lane >> 5;
  int b = blockIdx.x;          // 1024 = 128 bt x 8 h
  int h = b & 7, bt = b >> 3;
  const ushort* Qb = Q + ((size_t)bt * 256 + wv * 64) * 512 + h * 64;
  const ushort* Kb = K + ((size_t)bt * 256) * 512 + h * 64;
  const ushort* Vb = Vt + ((size_t)bt * 512 + h * 64) * 256;
  float c0 = mw[h] * mw[8 + h] * 0.125f;

  // stage K: 32 x 1KB instrs across 4 waves, LDS order == fragment-read order
#pragma unroll
  for (int i = 0; i < 8; i++) {
    int ci = (wv * 8 + i) * 64 + lane;
    int l2 = ci & 31, h2 = (ci >> 5) & 1, ds = (ci >> 6) & 3, kt = ci >> 8;
    gload_lds16(Kb + (size_t)(kt * 32 + l2) * 512 + ds * 16 + h2 * 8,
                &Klds[(wv * 8 + i) * 1024]);
  }
  // hoist Q as B-operand fragments (global, drains at first barrier)
  bf16x8 qf[2][4];
#pragma unroll
  for (int qj = 0; qj < 2; qj++)
#pragma unroll
    for (int ds = 0; ds < 4; ds++)
      qf[qj][ds] = *(const bf16x8*)(Qb + (size_t)(qj * 32 + lq) * 512 + ds * 16 + hi * 8);
  __syncthreads();

  // issue V staging now; it drains at the next barrier (hidden under pass A)
#pragma unroll
  for (int i = 0; i < 8; i++) {
    int ci = (wv * 8 + i) * 64 + lane;
    int l2 = ci & 31, h2 = (ci >> 5) & 1, df = (ci >> 6) & 1, ks = (ci >> 7) & 1, kt = ci >> 8;
    gload_lds16(Vb + (size_t)(df * 32 + l2) * 256 + kt * 32 + ks * 16 + h2 * 8,
                &Vlds[(wv * 8 + i) * 1024]);
  }

  // ---- pass A: row max of c0 * (Q.K), K from LDS ----
  float mx[2] = {-3.0e38f, -3.0e38f};
#pragma unroll 2
  for (int kt = 0; kt < 8; kt++) {
    bf16x8 kf[4];
#pragma unroll
    for (int ds = 0; ds < 4; ds++)
      kf[ds] = *(const bf16x8*)(&Klds[((kt * 4 + ds) * 2 + hi) * 512 + lq * 16]);
#pragma unroll
    for (int qj = 0; qj < 2; qj++) {
      f32x16 sT = zero16();
#pragma unroll
      for (int ds = 0; ds < 4; ds++)
        sT = __builtin_amdgcn_mfma_f32_32x32x16_bf16(kf[ds], qf[qj][ds], sT, 0, 0, 0);
#pragma unroll
      for (int r = 0; r < 16; r++) mx[qj] = fmaxf(mx[qj], sT[r] * c0);
    }
  }
#pragma unroll
  for (int qj = 0; qj < 2; qj++) mx[qj] = fmaxf(mx[qj], __shfl_xor(mx[qj], 32, 64));
  __syncthreads();   // V staged

  // ---- pass B: p = sigmoid(5*(s*c0 - mx)); row-sum and P.V ----
  float a5 = 5.f * c0;
  float m5[2] = {5.f * mx[0], 5.f * mx[1]};
  float sm[2] = {0.f, 0.f};
  f32x16 acc[2][2];
  acc[0][0] = zero16(); acc[0][1] = zero16(); acc[1][0] = zero16(); acc[1][1] = zero16();

#pragma unroll 2
  for (int kt = 0; kt < 8; kt++) {
    bf16x8 kf[4], vf[2][2];
#pragma unroll
    for (int ds = 0; ds < 4; ds++)
      kf[ds] = *(const bf16x8*)(&Klds[((kt * 4 + ds) * 2 + hi) * 512 + lq * 16]);
#pragma unroll
    for (int ks = 0; ks < 2; ks++)
#pragma unroll
      for (int df = 0; df < 2; df++)
        vf[ks][df] = *(const bf16x8*)(&Vlds[(((kt * 2 + ks) * 2 + df) * 2 + hi) * 512 + lq * 16]);
#pragma unroll
    for (int qj = 0; qj < 2; qj++) {
      f32x16 sT = zero16();
#pragma unroll
      for (int ds = 0; ds < 4; ds++)
        sT = __builtin_amdgcn_mfma_f32_32x32x16_bf16(kf[ds], qf[qj][ds], sT, 0, 0, 0);
      unsigned pk[8];
#pragma unroll
      for (int i = 0; i < 8; i++) {
        float p0 = rcpf(1.f + __expf(m5[qj] - sT[2 * i] * a5));
        float p1 = rcpf(1.f + __expf(m5[qj] - sT[2 * i + 1] * a5));
        sm[qj] += p0 + p1;
        pk[i] = cvtpk2(p0, p1);
      }
      // reg r holds k = (r&3) + 8*(r>>2) + 4*hi (+32*kt). Assemble A-frags:
#pragma unroll
      for (int ks = 0; ks < 2; ks++) {
        int bb = ks * 4;
        unsigned sa = (unsigned)__shfl_xor((int)pk[bb + 0], 32, 64);
        unsigned sb = (unsigned)__shfl_xor((int)pk[bb + 1], 32, 64);
        unsigned sc = (unsigned)__shfl_xor((int)pk[bb + 2], 32, 64);
        unsigned sd = (unsigned)__shfl_xor((int)pk[bb + 3], 32, 64);
        BF8U pa;
        pa.d[0] = hi ? sc : pk[bb + 0];
        pa.d[1] = hi ? sd : pk[bb + 1];
        pa.d[2] = hi ? pk[bb + 2] : sa;
        pa.d[3] = hi ? pk[bb + 3] : sb;
#pragma unroll
        for (int df = 0; df < 2; df++)
          acc[qj][df] = __builtin_amdgcn_mfma_f32_32x32x16_bf16(pa.v, vf[ks][df], acc[qj][df], 0, 0, 0);
      }
    }
  }

  // ---- epilogue: normalize by row-sum, write att[m][f] bf16 ----
#pragma unroll
  for (int qj = 0; qj < 2; qj++) sm[qj] += __shfl_xor(sm[qj], 32, 64);
  float rs[2] = {rcpf(sm[0] + 1e-8f), rcpf(sm[1] + 1e-8f)};
#pragma unroll
  for (int qj = 0; qj < 2; qj++) {
#pragma unroll
    for (int r = 0; r < 16; r++) {
      int ql = (r & 3) + 8 * (r >> 2) + 4 * hi;
      float rr = __shfl(rs[qj], ql, 64);
      size_t rowbase = ((size_t)bt * 256 + wv * 64 + qj * 32 + ql) * 512 + h * 64;
#pragma unroll
      for (int df = 0; df < 2; df++)
        att[rowbase + df * 32 + lq] = f2bf(acc[qj][df][r] * rr);
    }
  }
}

extern "C" void kernel_launch(void* const* d_in, const int* in_sizes, int n_in,
                              void* d_out, int out_size, void* d_ws, size_t ws_size,
                              hipStream_t stream) {
  (void)in_sizes; (void)n_in; (void)out_size; (void)ws_size;
  const float* qs  = (const float*)d_in[0];
  const float* ksn = (const float*)d_in[1];
  const float* vsn = (const float*)d_in[2];
  const float* Wq  = (const float*)d_in[3];
  const float* bq  = (const float*)d_in[4];
  const float* Wk  = (const float*)d_in[5];
  const float* bk  = (const float*)d_in[6];
  const float* Wv  = (const float*)d_in[7];
  const float* bv  = (const float*)d_in[8];
  const float* Wo  = (const float*)d_in[9];
  const float* bo  = (const float*)d_in[10];
  const float* mw  = (const float*)d_in[11];
  // d_in[12] = temporal_sync: constant along key axis -> cancels in spike softmax.

  char* ws = (char*)d_ws;
  ushort* Wt = (ushort*)ws;                                   // 4 * 512KiB bf16
  ushort* Qw = (ushort*)(ws + (size_t)(2u << 20));
  ushort* Kw = (ushort*)(ws + (size_t)(2u << 20) + 33554432u);
  ushort* Vt = (ushort*)(ws + (size_t)(2u << 20) + 2u * 33554432u);
  ushort* Aw = (ushort*)(ws + (size_t)(2u << 20) + 3u * 33554432u);

  wtrans_kernel<<<dim3(8, 8, 4), 256, 0, stream>>>(Wq, Wk, Wv, Wo, Wt);
  qkv_gemm_kernel<<<dim3(1024, 1, 3), 256, 0, stream>>>(qs, ksn, vsn, Wt, bq, bk, bv,
                                                        Qw, Kw, Vt);
  attn_kernel<<<dim3(1024), 256, 0, stream>>>(Qw, Kw, Vt, mw, Aw);
  out_gemm_kernel<<<dim3(1024), 256, 0, stream>>>(Aw, Wt + 3 * 262144, bo, (float*)d_out);
}